// Round 3
// baseline (13798.354 us; speedup 1.0000x reference)
//
#include <hip/hip_runtime.h>
#include <hip/hip_bf16.h>
#include <stdint.h>

// P_TNCN: seq=512, batch=128, states=512, out=256, inv_tau=0.5,
// alpha=0.01, beta=0.5.  float32 I/O (values on the bf16 grid).
//
// R3: MFMA-ized scan. 128 blocks (1 batch row each) x 512 threads (8 waves).
// Matvecs via v_mfma_f32_16x16x32_bf16 with all 16 A-rows loaded identical
// (every row of D = the matvec; every lane holds out[n0 + lane%16] in every
// acc reg -> uniform in-lane state update, no divergence, no owner phase).
// Weights pre-packed into exact B-fragment order so the hot loop is pure
// coalesced global_load_dwordx4 -> MFMA. 3 __syncthreads/step (down from 4).
// Expected regime: L2->CU weight stream bound (~1 MB/step/CU).

#define SEQ   512
#define BATCH 128
#define SD    512
#define OD    256

typedef float f32x4  __attribute__((ext_vector_type(4)));
typedef short bf16x8 __attribute__((ext_vector_type(8)));

__device__ __forceinline__ uint32_t f32_to_bf16u(float f) {
    uint32_t u = __float_as_uint(f);
    return (u + 0x7fffu + ((u >> 16) & 1u)) >> 16;   // RTNE
}
__device__ __forceinline__ uint32_t pack_bf2(float a, float b) {
    return f32_to_bf16u(a) | (f32_to_bf16u(b) << 16);
}
__device__ __forceinline__ float tanh_fast(float x) {
    float e = __expf(2.0f * x);
    return 1.0f - 2.0f / (e + 1.0f);
}

// ---------------------------------------------------------------------------
// Fragment-pack kernel.  B-frag layout for mfma_f32_16x16x32_bf16:
//   lane L holds B[k = (L>>4)*8 + j][n = L&15], j=0..7  (8 bf16 = 16 B)
// With B = W^T (W row-major [N][K]): lane L's 16 B = W[n0+(L&15)][k0+(L>>4)*8 .. +7]
// Images (uint4 per lane):
//   FB_A (w_r, N=512,K=512): frag[(nt*16+kt)*64 + L]   32768 uint4  (512 KB)
//   FB_O (w_o, N=256,K=512): frag[(nt*16+kt)*64 + L]   16384 uint4  (256 KB)
//   FB_F (w_f, N=512,K=256): frag[(nt* 8+kt)*64 + L]   16384 uint4  (256 KB)
// ---------------------------------------------------------------------------
__global__ void pack_frags(const float* __restrict__ w_o,
                           const float* __restrict__ w_r,
                           const float* __restrict__ w_f,
                           uint4* __restrict__ ws)
{
    int gid = blockIdx.x * 256 + threadIdx.x;           // 65536 total
    const float* src; int N, K, base, i;
    if (gid < 32768)      { src = w_r; N = 512; K = 512; base = 0;     i = gid; }
    else if (gid < 49152) { src = w_o; N = 256; K = 512; base = 32768; i = gid - 32768; }
    else                  { src = w_f; N = 512; K = 256; base = 49152; i = gid - 49152; }
    int L   = i & 63;
    int tile = i >> 6;                 // nt*KT + kt, kt fastest
    int KT  = K / 32;
    int nt  = tile / KT;
    int kt  = tile - nt * KT;
    int n   = nt * 16 + (L & 15);
    int k0  = kt * 32 + (L >> 4) * 8;
    const float* p = &src[n * K + k0];
    uint4 v;
    v.x = pack_bf2(p[0], p[1]);
    v.y = pack_bf2(p[2], p[3]);
    v.z = pack_bf2(p[4], p[5]);
    v.w = pack_bf2(p[6], p[7]);
    ws[base + gid - (base ? (base == 32768 ? 32768 : 49152) : 0)] = v;  // == ws[gid]
}

// ---------------------------------------------------------------------------
// Main scan.
// ---------------------------------------------------------------------------
__global__ __launch_bounds__(512)
void tncn_scan(const float* __restrict__ x,       // [512][128][256]
               const float* __restrict__ h_init,  // [128][512]
               const float* __restrict__ b_o,     // [256]
               const float* __restrict__ b_r,     // [512]
               const uint4* __restrict__ ws,
               float* __restrict__ out)           // [512][128][256]
{
    const bf16x8* FB_A = (const bf16x8*)ws;            // [32][16][64]
    const bf16x8* FB_O = (const bf16x8*)(ws + 32768);  // [16][16][64]
    const bf16x8* FB_F = (const bf16x8*)(ws + 49152);  // [32][ 8][64]

    __shared__ __align__(16) unsigned short thbf [SD];  // bf16 tanh(h_post)
    __shared__ __align__(16) unsigned short thpbf[SD];  // bf16 tanh(h_prior)
    __shared__ __align__(16) unsigned short errbf[OD];  // bf16 error

    const int b    = blockIdx.x;
    const int tid  = threadIdx.x;
    const int w    = tid >> 6;       // wave 0..7
    const int lane = tid & 63;
    const int lm   = lane & 15;      // MFMA col
    const int lk   = lane >> 4;      // k-subgroup 0..3

    // Per-lane row indices: phase A/C tiles nt = w*4+ntl (s = nt*16+lm),
    // phase B tiles nt2 = w*2+ntl2 (o = nt2*16+lm).
    float br4[4], hpost[4], hp[4];
    #pragma unroll
    for (int ntl = 0; ntl < 4; ++ntl) {
        int s = w * 64 + ntl * 16 + lm;
        br4[ntl]   = b_r[s];
        hpost[ntl] = h_init[b * SD + s];
    }
    float bo2[2];
    #pragma unroll
    for (int ntl = 0; ntl < 2; ++ntl)
        bo2[ntl] = b_o[w * 32 + ntl * 16 + lm];

    if (lk == 0) {
        #pragma unroll
        for (int ntl = 0; ntl < 4; ++ntl) {
            int s = w * 64 + ntl * 16 + lm;
            thbf[s] = (unsigned short)f32_to_bf16u(tanh_fast(hpost[ntl]));
        }
    }
    __syncthreads();

    const bf16x8* pA = FB_A + w * 4096 + lane;   // + ntl*1024 + kt*64
    const bf16x8* pO = FB_O + w * 2048 + lane;   // + ntl2*1024 + kt*64
    const bf16x8* pF = FB_F + w * 2048 + lane;   // + ntl*512  + kt*64

    for (int t = 0; t < SEQ; ++t) {
        // ---- Phase A: acc[s] = tanh(h) @ w_r^T   (N=512, K=512)
        f32x4 accA[4] = {{0,0,0,0},{0,0,0,0},{0,0,0,0},{0,0,0,0}};
        #pragma unroll
        for (int kt = 0; kt < 16; ++kt) {
            bf16x8 aF = *(const bf16x8*)&thbf[kt * 32 + lk * 8];
            #pragma unroll
            for (int ntl = 0; ntl < 4; ++ntl) {
                bf16x8 bF = pA[ntl * 1024 + kt * 64];
                accA[ntl] = __builtin_amdgcn_mfma_f32_16x16x32_bf16(aF, bF, accA[ntl], 0, 0, 0);
            }
        }
        #pragma unroll
        for (int ntl = 0; ntl < 4; ++ntl) {
            hp[ntl] = 0.5f * hpost[ntl] + 0.5f * (accA[ntl][0] + br4[ntl]);
            if (lk == 0) {
                int s = w * 64 + ntl * 16 + lm;
                thpbf[s] = (unsigned short)f32_to_bf16u(tanh_fast(hp[ntl]));
            }
        }
        __syncthreads();   // #1: thpbf ready

        // ---- Phase B: xp[o] = tanh(h_prior) @ w_o^T   (N=256, K=512)
        f32x4 accB[2] = {{0,0,0,0},{0,0,0,0}};
        #pragma unroll
        for (int kt = 0; kt < 16; ++kt) {
            bf16x8 aF = *(const bf16x8*)&thpbf[kt * 32 + lk * 8];
            #pragma unroll
            for (int ntl = 0; ntl < 2; ++ntl) {
                bf16x8 bF = pO[ntl * 1024 + kt * 64];
                accB[ntl] = __builtin_amdgcn_mfma_f32_16x16x32_bf16(aF, bF, accB[ntl], 0, 0, 0);
            }
        }
        if (lk == 0) {
            #pragma unroll
            for (int ntl = 0; ntl < 2; ++ntl) {
                int o   = w * 32 + ntl * 16 + lm;
                int idx = (t * BATCH + b) * OD + o;
                float e = accB[ntl][0] + bo2[ntl] - x[idx];
                out[idx] = e;
                errbf[o] = (unsigned short)f32_to_bf16u(e);
            }
        }
        __syncthreads();   // #2: errbf ready

        // ---- Phase C: corr[s] = err @ w_f^T   (N=512, K=256)
        f32x4 accC[4] = {{0,0,0,0},{0,0,0,0},{0,0,0,0},{0,0,0,0}};
        #pragma unroll
        for (int kt = 0; kt < 8; ++kt) {
            bf16x8 aF = *(const bf16x8*)&errbf[kt * 32 + lk * 8];
            #pragma unroll
            for (int ntl = 0; ntl < 4; ++ntl) {
                bf16x8 bF = pF[ntl * 512 + kt * 64];
                accC[ntl] = __builtin_amdgcn_mfma_f32_16x16x32_bf16(aF, bF, accC[ntl], 0, 0, 0);
            }
        }
        #pragma unroll
        for (int ntl = 0; ntl < 4; ++ntl) {
            float h  = hp[ntl];
            float sg = (h > 0.0f) ? 1.0f : ((h < 0.0f) ? -1.0f : 0.0f);
            hpost[ntl] = h - 0.01f * sg - 0.5f * accC[ntl][0];
            if (lk == 0) {
                int s = w * 64 + ntl * 16 + lm;
                thbf[s] = (unsigned short)f32_to_bf16u(tanh_fast(hpost[ntl]));
            }
        }
        __syncthreads();   // #3: thbf ready for next step
    }
}

extern "C" void kernel_launch(void* const* d_in, const int* in_sizes, int n_in,
                              void* d_out, int out_size, void* d_ws, size_t ws_size,
                              hipStream_t stream)
{
    // setup_inputs order: x, h_init, w_o, b_o, w_r, b_r, w_f, w_i
    const float* x  = (const float*)d_in[0];
    const float* h0 = (const float*)d_in[1];
    const float* wo = (const float*)d_in[2];
    const float* bo = (const float*)d_in[3];
    const float* wr = (const float*)d_in[4];
    const float* br = (const float*)d_in[5];
    const float* wf = (const float*)d_in[6];
    // d_in[7] (w_i) multiplies a zeros tensor in the reference — unused.

    uint4* ws = (uint4*)d_ws;
    float* out = (float*)d_out;

    pack_frags<<<256, 256, 0, stream>>>(wo, wr, wf, ws);   // 65536 frags, 1 MiB
    tncn_scan<<<BATCH, 512, 0, stream>>>(x, h0, bo, br, ws, out);
}

// Round 4
// 11512.586 us; speedup vs baseline: 1.1985x; 1.1985x over previous
//
#include <hip/hip_runtime.h>
#include <stdint.h>

// P_TNCN R4: folded scan. seq=512, batch=128, states=512, out=256.
//   h_prior = 0.5 h + 0.5 (tanh(h) @ w_r^T + b_r)
//   h_post  = h_prior - 0.01 sign(h_prior) - 0.5 tanh(h_prior) @ W_fo^T + P_t
//     where W_fo = w_f @ w_o,  P_t = 0.5 (x_t - b_o) @ w_f^T   (precomputed)
//   error_t = tanh(h_prior) @ w_o^T + b_o - x_t                (epilogue GEMM)
// P and G=tanh(h_prior) overlay d_out rows (1024 B/row), scan replaces P row
// by G row in-place per step. 8 scan blocks x 16 batch rows (real M=16 MFMA).

#define SEQ   512
#define BATCH 128
#define SD    512
#define OD    256
#define TS    520          // LDS row stride (shorts) for 512-wide tanh images
#define PINR  5            // w_r  k-tiles pinned in regs per n-tile
#define PINF  3            // W_fo k-tiles pinned in regs per n-tile

typedef float f32x4  __attribute__((ext_vector_type(4)));
typedef short bf16x8 __attribute__((ext_vector_type(8)));

// ws layout (uint4 units):
//  RF [     0, 32768): w_r  frags [32 nt][16 kt][64]   512 KB
//  FF [ 32768, 65536): W_fo frags [32 nt][16 kt][64]   512 KB
//  OF [ 65536, 81920): w_o  frags [16 nt][16 kt][64]   256 KB
//  WF [ 81920, 98304): w_f  frags [32 nt][ 8 kt][64]   256 KB
#define RF_BASE 0
#define FF_BASE 32768
#define OF_BASE 65536
#define WF_BASE 81920

__device__ __forceinline__ uint32_t f32_to_bf16u(float f) {
    uint32_t u = __float_as_uint(f);
    return (u + 0x7fffu + ((u >> 16) & 1u)) >> 16;   // RTNE
}
__device__ __forceinline__ uint32_t pack_bf2(float a, float b) {
    return f32_to_bf16u(a) | (f32_to_bf16u(b) << 16);
}
__device__ __forceinline__ float bfval(uint32_t v) { return __uint_as_float(v << 16); }
__device__ __forceinline__ float tanh_fast(float x) {
    float e = __expf(2.0f * x);
    return 1.0f - 2.0f / (e + 1.0f);
}

// --------------------------------------------------------------------------
// Pack RF / OF / WF from raw f32 weights. B-frag (16x16x32 bf16, verified):
// lane L holds W[n = nt*16 + (L&15)][k = kt*32 + (L>>4)*8 + j], j=0..7.
// --------------------------------------------------------------------------
__global__ void pack_frags(const float* __restrict__ w_r,
                           const float* __restrict__ w_o,
                           const float* __restrict__ w_f,
                           uint4* __restrict__ ws)
{
    int gid = blockIdx.x * 256 + threadIdx.x;          // 65536
    const float* src; int K, KT, dst;
    int i;
    if (gid < 32768)      { src = w_r; K = 512; KT = 16; dst = RF_BASE; i = gid; }
    else if (gid < 49152) { src = w_o; K = 512; KT = 16; dst = OF_BASE; i = gid - 32768; }
    else                  { src = w_f; K = 256; KT = 8;  dst = WF_BASE; i = gid - 49152; }
    int L    = i & 63;
    int tile = i >> 6;
    int nt   = tile / KT;
    int kt   = tile - nt * KT;
    int n    = nt * 16 + (L & 15);
    int k0   = kt * 32 + (L >> 4) * 8;
    const float* p = &src[n * K + k0];
    uint4 v;
    v.x = pack_bf2(p[0], p[1]);
    v.y = pack_bf2(p[2], p[3]);
    v.z = pack_bf2(p[4], p[5]);
    v.w = pack_bf2(p[6], p[7]);
    ws[dst + i] = v;
}

// --------------------------------------------------------------------------
// Build W_fo = w_f @ w_o  ([512,256]@[256,512] -> [512,512]) in f32, scatter
// directly into FF frag layout as bf16.
// grid (64,2) x 256 threads: 8 n-rows per block, k = by*256+tid.
// --------------------------------------------------------------------------
__global__ __launch_bounds__(256)
void build_Wfo_frags(const float* __restrict__ w_f,
                     const float* __restrict__ w_o,
                     uint4* __restrict__ ws)
{
    __shared__ float wfsh[8 * 256];
    int n0  = blockIdx.x * 8;
    int tid = threadIdx.x;
    int k   = blockIdx.y * 256 + tid;
    #pragma unroll
    for (int j = 0; j < 8; ++j) {
        int idx = j * 256 + tid;
        wfsh[idx] = w_f[n0 * 256 + idx];
    }
    __syncthreads();
    float acc[8] = {0,0,0,0,0,0,0,0};
    for (int o = 0; o < 256; ++o) {
        float wv = w_o[o * 512 + k];
        #pragma unroll
        for (int r = 0; r < 8; ++r) acc[r] += wfsh[r * 256 + o] * wv;
    }
    unsigned short* FFs = (unsigned short*)(ws + FF_BASE);
    int kt   = k >> 5;
    int lane16 = ((k >> 3) & 3) << 4;
    int j    = k & 7;
    #pragma unroll
    for (int r = 0; r < 8; ++r) {
        int n  = n0 + r;
        int nt = n >> 4;
        int lane = (n & 15) + lane16;
        FFs[(((nt * 16) + kt) * 64 + lane) * 8 + j] = (unsigned short)f32_to_bf16u(acc[r]);
    }
}

// --------------------------------------------------------------------------
// Pre-GEMM: P[m][s] = 0.5 * sum_o (x[m][o]-b_o[o]) * w_f[s][o], bf16 rows
// overlaid into d_out (1024 B per row m). 4096 blocks x 512 thr, 16 rows each.
// --------------------------------------------------------------------------
__global__ __launch_bounds__(512)
void pregemm_P(const float* __restrict__ x,
               const float* __restrict__ b_o,
               const uint4* __restrict__ ws,
               unsigned short* __restrict__ Pout)
{
    __shared__ unsigned short Aimg[16 * 264];
    __shared__ float bo_sh[256];
    int m0  = blockIdx.x * 16;
    int tid = threadIdx.x;
    if (tid < 256) bo_sh[tid] = b_o[tid];
    __syncthreads();
    {
        int row = tid >> 5, c0 = (tid & 31) * 8;
        const float* xr = &x[(m0 + row) * 256 + c0];
        unsigned short* ar = &Aimg[row * 264 + c0];
        #pragma unroll
        for (int j = 0; j < 8; ++j)
            ar[j] = (unsigned short)f32_to_bf16u(xr[j] - bo_sh[c0 + j]);
    }
    __syncthreads();
    int w = tid >> 6, lane = tid & 63, lm = lane & 15, lq = lane >> 4;
    const bf16x8* pB = (const bf16x8*)(ws + WF_BASE) + w * 2048 + lane;  // [4 nt][8 kt][64]
    f32x4 acc[4] = {{0,0,0,0},{0,0,0,0},{0,0,0,0},{0,0,0,0}};
    #pragma unroll
    for (int kt = 0; kt < 8; ++kt) {
        bf16x8 aF = *(const bf16x8*)&Aimg[lm * 264 + kt * 32 + lq * 8];
        #pragma unroll
        for (int ntl = 0; ntl < 4; ++ntl)
            acc[ntl] = __builtin_amdgcn_mfma_f32_16x16x32_bf16(aF, pB[ntl * 512 + kt * 64], acc[ntl], 0, 0, 0);
    }
    #pragma unroll
    for (int ntl = 0; ntl < 4; ++ntl)
        #pragma unroll
        for (int r = 0; r < 4; ++r) {
            int m = m0 + lq * 4 + r;
            int n = w * 64 + ntl * 16 + lm;
            Pout[m * 512 + n] = (unsigned short)f32_to_bf16u(0.5f * acc[ntl][r]);
        }
}

// --------------------------------------------------------------------------
// Sequential scan: 8 blocks x 512 thr, 16 batch rows per block.
// --------------------------------------------------------------------------
__global__ __launch_bounds__(512, 2)
void tncn_scan(const float* __restrict__ h_init,
               const float* __restrict__ b_r,
               const uint4* __restrict__ ws,
               uint4* __restrict__ outq)          // d_out as uint4 (P in, G out)
{
    __shared__ unsigned short Tp[16 * TS];
    __shared__ unsigned short Tq[16 * TS];
    __shared__ unsigned short Pb[16 * TS];

    const int b0   = blockIdx.x * 16;
    const int tid  = threadIdx.x;
    const int w    = tid >> 6;
    const int lane = tid & 63;
    const int lm   = lane & 15;
    const int lq   = lane >> 4;
    const int row  = tid >> 5;       // for P/G row moves
    const int c    = tid & 31;

    const bf16x8* pR = (const bf16x8*)(ws + RF_BASE) + w * 4096 + lane;  // [4 nt][16 kt][64]
    const bf16x8* pF = (const bf16x8*)(ws + FF_BASE) + w * 4096 + lane;

    float h[4][4], br4[4];
    #pragma unroll
    for (int ntl = 0; ntl < 4; ++ntl) {
        int n = w * 64 + ntl * 16 + lm;
        br4[ntl] = b_r[n];
        #pragma unroll
        for (int r = 0; r < 4; ++r)
            h[ntl][r] = h_init[(b0 + lq * 4 + r) * SD + n];
    }

    bf16x8 pinR[4][PINR], pinF[4][PINF];
    #pragma unroll
    for (int ntl = 0; ntl < 4; ++ntl) {
        #pragma unroll
        for (int kt = 0; kt < PINR; ++kt) pinR[ntl][kt] = pR[(ntl * 16 + kt) * 64];
        #pragma unroll
        for (int kt = 0; kt < PINF; ++kt) pinF[ntl][kt] = pF[(ntl * 16 + kt) * 64];
    }

    #pragma unroll
    for (int ntl = 0; ntl < 4; ++ntl)
        #pragma unroll
        for (int r = 0; r < 4; ++r)
            Tp[(lq * 4 + r) * TS + w * 64 + ntl * 16 + lm] =
                (unsigned short)f32_to_bf16u(tanh_fast(h[ntl][r]));
    __syncthreads();

    for (int t = 0; t < SEQ; ++t) {
        // issue P-row loads (consumed after barrier 1)
        const uint4* Psrc = outq + ((size_t)(t * BATCH + b0 + row)) * 64 + c * 2;
        uint4 p0 = Psrc[0], p1 = Psrc[1];

        // ---- matvec1: acc = tanh(h_post) @ w_r^T
        f32x4 acc[4] = {{0,0,0,0},{0,0,0,0},{0,0,0,0},{0,0,0,0}};
        #pragma unroll
        for (int kt = 0; kt < 16; ++kt) {
            bf16x8 aF = *(const bf16x8*)&Tp[lm * TS + kt * 32 + lq * 8];
            #pragma unroll
            for (int ntl = 0; ntl < 4; ++ntl) {
                bf16x8 bF = (kt < PINR) ? pinR[ntl][kt] : pR[(ntl * 16 + kt) * 64];
                acc[ntl] = __builtin_amdgcn_mfma_f32_16x16x32_bf16(aF, bF, acc[ntl], 0, 0, 0);
            }
        }
        #pragma unroll
        for (int ntl = 0; ntl < 4; ++ntl)
            #pragma unroll
            for (int r = 0; r < 4; ++r) {
                float hp = 0.5f * h[ntl][r] + 0.5f * (acc[ntl][r] + br4[ntl]);
                h[ntl][r] = hp;   // h now holds h_prior
                Tq[(lq * 4 + r) * TS + w * 64 + ntl * 16 + lm] =
                    (unsigned short)f32_to_bf16u(tanh_fast(hp));
            }
        // park P rows in LDS
        *(uint4*)&Pb[row * TS + c * 16]     = p0;
        *(uint4*)&Pb[row * TS + c * 16 + 8] = p1;
        __syncthreads();   // #1: Tq + Pb ready

        // G-row store (tanh(h_prior) replaces P row in d_out)
        {
            uint4 g0 = *(const uint4*)&Tq[row * TS + c * 16];
            uint4 g1 = *(const uint4*)&Tq[row * TS + c * 16 + 8];
            uint4* Gdst = outq + ((size_t)(t * BATCH + b0 + row)) * 64 + c * 2;
            Gdst[0] = g0; Gdst[1] = g1;
        }

        // ---- matvec2: corr = tanh(h_prior) @ W_fo^T
        f32x4 acc2[4] = {{0,0,0,0},{0,0,0,0},{0,0,0,0},{0,0,0,0}};
        #pragma unroll
        for (int kt = 0; kt < 16; ++kt) {
            bf16x8 aF = *(const bf16x8*)&Tq[lm * TS + kt * 32 + lq * 8];
            #pragma unroll
            for (int ntl = 0; ntl < 4; ++ntl) {
                bf16x8 bF = (kt < PINF) ? pinF[ntl][kt] : pF[(ntl * 16 + kt) * 64];
                acc2[ntl] = __builtin_amdgcn_mfma_f32_16x16x32_bf16(aF, bF, acc2[ntl], 0, 0, 0);
            }
        }
        #pragma unroll
        for (int ntl = 0; ntl < 4; ++ntl)
            #pragma unroll
            for (int r = 0; r < 4; ++r) {
                float hp = h[ntl][r];
                float pv = bfval((uint32_t)Pb[(lq * 4 + r) * TS + w * 64 + ntl * 16 + lm]);
                float sg = (hp > 0.0f) ? 1.0f : ((hp < 0.0f) ? -1.0f : 0.0f);
                float hn = hp - 0.01f * sg - 0.5f * acc2[ntl][r] + pv;
                h[ntl][r] = hn;
                Tp[(lq * 4 + r) * TS + w * 64 + ntl * 16 + lm] =
                    (unsigned short)f32_to_bf16u(tanh_fast(hn));
            }
        __syncthreads();   // #2: Tp ready for next step
    }
}

// --------------------------------------------------------------------------
// Epilogue: error[m][o] = G[m][:] @ w_o^T + b_o[o] - x[m][o], in-place over
// the G rows of d_out. 4096 blocks x 512 thr, 16 rows each.
// --------------------------------------------------------------------------
__global__ __launch_bounds__(512)
void epilogue_err(const float* __restrict__ x,
                  const float* __restrict__ b_o,
                  const uint4* __restrict__ ws,
                  float* __restrict__ outf)
{
    __shared__ unsigned short Gimg[16 * TS];
    int m0  = blockIdx.x * 16;
    int tid = threadIdx.x;
    {
        int row = tid >> 5, c = tid & 31;
        const uint4* src = (const uint4*)outf + ((size_t)(m0 + row)) * 64 + c * 2;
        uint4 v0 = src[0], v1 = src[1];
        *(uint4*)&Gimg[row * TS + c * 16]     = v0;
        *(uint4*)&Gimg[row * TS + c * 16 + 8] = v1;
    }
    __syncthreads();
    int w = tid >> 6, lane = tid & 63, lm = lane & 15, lq = lane >> 4;
    float bo2[2];
    #pragma unroll
    for (int ntl = 0; ntl < 2; ++ntl) bo2[ntl] = b_o[w * 32 + ntl * 16 + lm];
    const bf16x8* pB = (const bf16x8*)(ws + OF_BASE) + w * 2048 + lane;  // [2 nt][16 kt][64]
    f32x4 acc[2] = {{0,0,0,0},{0,0,0,0}};
    #pragma unroll
    for (int kt = 0; kt < 16; ++kt) {
        bf16x8 aF = *(const bf16x8*)&Gimg[lm * TS + kt * 32 + lq * 8];
        #pragma unroll
        for (int ntl = 0; ntl < 2; ++ntl)
            acc[ntl] = __builtin_amdgcn_mfma_f32_16x16x32_bf16(aF, pB[ntl * 1024 + kt * 64], acc[ntl], 0, 0, 0);
    }
    #pragma unroll
    for (int ntl = 0; ntl < 2; ++ntl)
        #pragma unroll
        for (int r = 0; r < 4; ++r) {
            int m = m0 + lq * 4 + r;
            int o = w * 32 + ntl * 16 + lm;
            outf[m * 256 + o] = acc[ntl][r] + bo2[ntl] - x[m * 256 + o];
        }
}

extern "C" void kernel_launch(void* const* d_in, const int* in_sizes, int n_in,
                              void* d_out, int out_size, void* d_ws, size_t ws_size,
                              hipStream_t stream)
{
    // setup_inputs order: x, h_init, w_o, b_o, w_r, b_r, w_f, w_i
    const float* x  = (const float*)d_in[0];
    const float* h0 = (const float*)d_in[1];
    const float* wo = (const float*)d_in[2];
    const float* bo = (const float*)d_in[3];
    const float* wr = (const float*)d_in[4];
    const float* br = (const float*)d_in[5];
    const float* wf = (const float*)d_in[6];
    // d_in[7] (w_i) multiplies zeros in the reference — unused.

    uint4* ws = (uint4*)d_ws;

    pack_frags<<<256, 256, 0, stream>>>(wr, wo, wf, ws);
    build_Wfo_frags<<<dim3(64, 2), 256, 0, stream>>>(wf, wo, ws);
    pregemm_P<<<4096, 512, 0, stream>>>(x, bo, ws, (unsigned short*)d_out);
    tncn_scan<<<8, 512, 0, stream>>>(h0, br, ws, (uint4*)d_out);
    epilogue_err<<<4096, 512, 0, stream>>>(x, bo, ws, (float*)d_out);
}